// Round 1
// baseline (145.994 us; speedup 1.0000x reference)
//
#include <hip/hip_runtime.h>
#include <hip/hip_fp16.h>

#define Bsz 256
#define Nn  1152
#define Kk  10
#define NT  576      // 9 waves
#define NW  9
#define SJ  1154     // uint2 stride per o-pair row: 2*1154 mod 32 = 4 -> 8 distinct bank-pairs

#define W_ELEMS (Kk*Nn*128)     // 1474560
#define U_ELEMS (Bsz*Nn*8)      // 2359296
#define WCELLS  (Kk*Nn)         // 11520 cells of 8x16
#define WBLKS   (WCELLS/16)     // 720 transpose blocks
#define UBLKS   (U_ELEMS/8/256) // 1152 u-convert blocks

typedef _Float16 hf2_t __attribute__((ext_vector_type(2)));

static __device__ __forceinline__ unsigned pkh2(float x, float y) {
    __half2 h = __floats2half2_rn(x, y);
    return *reinterpret_cast<unsigned*>(&h);
}
static __device__ __forceinline__ float2 uph2(unsigned v) {
    __half2 h;
    *reinterpret_cast<unsigned*>(&h) = v;
    return __half22float2(h);
}
// v_dot2_f32_f16: c += a.lo*b.lo + a.hi*b.hi  (f32 accumulate, 1 inst)
static __device__ __forceinline__ float fdot2u(unsigned a, unsigned b, float c) {
    union { unsigned u; hf2_t h; } A, B;
    A.u = a; B.u = b;
    return __builtin_amdgcn_fdot2(A.h, B.h, c, false);
}

#define PERM_LO 0x01000504u   // half2(lo16(src0), lo16(src1))
#define PERM_HI 0x03020706u   // half2(hi16(src0), hi16(src1))
#define ONE2    0x3C003C00u   // half2(1, 1)

// W: fp32 [K][N][8 i][16 o] -> Wh: fp16 [K][N][16 o][8 i]  (per-cell transpose so the
// i-contraction is half2-contiguous for v_dot2).  u: fp32 -> fp16, layout unchanged.
__global__ void cvt_kernel(const float* __restrict__ W, const float* __restrict__ u,
                           unsigned* __restrict__ Wh, __half2* __restrict__ uh) {
    const int t = threadIdx.x;
    if ((int)blockIdx.x < WBLKS) {
        __shared__ float ws[16 * 132];           // 16 cells x 128, stride 132 (pad: 4c+16i+o banks)
        const size_t base = (size_t)blockIdx.x * (16 * 128);
        const float4* p = (const float4*)(W + base) + t * 2;
        const float4 x = p[0], y = p[1];
        {
            const int e = t * 8;                 // element index within block chunk
            float* d = ws + (e >> 7) * 132 + (e & 127);
            d[0]=x.x; d[1]=x.y; d[2]=x.z; d[3]=x.w;
            d[4]=y.x; d[5]=y.y; d[6]=y.z; d[7]=y.w;
        }
        __syncthreads();
        const int c = t >> 4, o = t & 15;        // one o-row per thread
        const float* s = ws + c * 132 + o;
        uint4 r;
        r.x = pkh2(s[0*16], s[1*16]);
        r.y = pkh2(s[2*16], s[3*16]);
        r.z = pkh2(s[4*16], s[5*16]);
        r.w = pkh2(s[6*16], s[7*16]);
        *(uint4*)(Wh + ((size_t)blockIdx.x * 16 + c) * 64 + o * 4) = r;
    } else {
        const int j = ((int)blockIdx.x - WBLKS) * 256 + t;   // < 294912
        const float4* p = (const float4*)u + (size_t)j * 2;
        __half2* o = uh + (size_t)j * 4;
        const float4 a = p[0], b = p[1];
        o[0] = __floats2half2_rn(a.x, a.y);
        o[1] = __floats2half2_rn(a.z, a.w);
        o[2] = __floats2half2_rn(b.x, b.y);
        o[3] = __floats2half2_rn(b.z, b.w);
    }
}

// One block per (bg, k): b-pair b0,b0+1. u_hat fp16 in LDS (b0/b1 interleaved uint2,
// stride SJ). Routing with e-trick softmax. All hot inner loops use v_dot2_f32_f16.
template<bool HALF>
__global__ __launch_bounds__(NT, 2)
void digitcaps_kernel(const float* __restrict__ u32, const float* __restrict__ W32,
                      const __half* __restrict__ uh, const __half* __restrict__ Wh,
                      float* __restrict__ out)
{
    const int t    = threadIdx.x;
    const int lane = t & 63;
    const int wav  = t >> 6;
    const int bg   = blockIdx.x;     // 0..127
    const int k    = blockIdx.y;     // 0..9
    const int b0   = bg * 2;

    __shared__ uint2    uhS[8 * SJ];        // 73856 B
    __shared__ unsigned cS2[Nn];            // 4608 B  half2(e_b0, e_b1) per n
    __shared__ float    redS[2 * NW * 17];  // 1224 B
    __shared__ __align__(16) float vS[32];  // 128 B
    __shared__ float    mS[2];              // 8 B
    // total ~79.8 KB -> 2 blocks/CU (VGPR must stay <=64 to keep 18 waves resident)

    // ---------------- Phase 1: u_hat = u . W ----------------
    {
        const int oh   = t & 1;
        const int nsub = t >> 1;
        for (int r = 0; r < 4; ++r) {
            const int n = r * 288 + nsub;
            float a0[8], a1[8];
            if (HALF) {
                // u as 4 packed half2 per b; W rows [o][i] as 4 packed half2: pure dot2
                const uint4 qa = *(const uint4*)(uh + ((size_t)b0 * Nn + n) * 8);
                const uint4 qb = *(const uint4*)(uh + ((size_t)(b0 + 1) * Nn + n) * 8);
                #pragma unroll
                for (int o = 0; o < 8; ++o) {
                    const uint4 w = *(const uint4*)(Wh + (((size_t)(k * Nn + n)) * 16 + oh * 8 + o) * 8);
                    float s0 = 0.f, s1 = 0.f;
                    s0 = fdot2u(qa.x, w.x, s0); s1 = fdot2u(qb.x, w.x, s1);
                    s0 = fdot2u(qa.y, w.y, s0); s1 = fdot2u(qb.y, w.y, s1);
                    s0 = fdot2u(qa.z, w.z, s0); s1 = fdot2u(qb.z, w.z, s1);
                    s0 = fdot2u(qa.w, w.w, s0); s1 = fdot2u(qb.w, w.w, s1);
                    a0[o] = s0; a1[o] = s1;
                }
            } else {
                float ua[8], ub[8];
                const float4* up0 = (const float4*)(u32 + ((size_t)b0 * Nn + n) * 8);
                const float4* up1 = (const float4*)(u32 + ((size_t)(b0 + 1) * Nn + n) * 8);
                const float4 x0 = up0[0], x1 = up0[1];
                const float4 y0 = up1[0], y1 = up1[1];
                ua[0]=x0.x; ua[1]=x0.y; ua[2]=x0.z; ua[3]=x0.w;
                ua[4]=x1.x; ua[5]=x1.y; ua[6]=x1.z; ua[7]=x1.w;
                ub[0]=y0.x; ub[1]=y0.y; ub[2]=y0.z; ub[3]=y0.w;
                ub[4]=y1.x; ub[5]=y1.y; ub[6]=y1.z; ub[7]=y1.w;
                #pragma unroll
                for (int o = 0; o < 8; ++o) { a0[o] = 0.f; a1[o] = 0.f; }
                #pragma unroll
                for (int i = 0; i < 8; ++i) {
                    const float4* wp = (const float4*)(W32 + ((size_t)k * Nn + n) * 128) + oh * 2 + i * 4;
                    const float4 w0 = wp[0], w1 = wp[1];
                    float wv[8];
                    wv[0]=w0.x; wv[1]=w0.y; wv[2]=w0.z; wv[3]=w0.w;
                    wv[4]=w1.x; wv[5]=w1.y; wv[6]=w1.z; wv[7]=w1.w;
                    const float x = ua[i], y = ub[i];
                    #pragma unroll
                    for (int o = 0; o < 8; ++o) { a0[o] += x * wv[o]; a1[o] += y * wv[o]; }
                }
            }
            #pragma unroll
            for (int jj = 0; jj < 4; ++jj) {
                const int j = oh * 4 + jj;
                uhS[j * SJ + n] = make_uint2(pkh2(a0[2*jj], a0[2*jj+1]),
                                             pkh2(a1[2*jj], a1[2*jj+1]));
            }
        }
    }
    __syncthreads();

    // ---------------- Phase 2: routing ----------------
    float lg0[2] = {0.f, 0.f}, lg1[2] = {0.f, 0.f};
    unsigned vh0[8], vh1[8];        // v packed as half2 per o-pair
    const int j_s = lane & 7;
    const int g_s = lane >> 3;

    for (int it = 0; it < 3; ++it) {
        if (it > 0) {
            // ---- a-scan: logits += u_hat . v  (rows n = t, t+NT) ----
            #pragma unroll
            for (int r = 0; r < 2; ++r) {
                const int n = t + r * NT;
                float acc0 = 0.f, acc1 = 0.f;
                #pragma unroll
                for (int j = 0; j < 8; ++j) {
                    const uint2 q = uhS[j * SJ + n];
                    acc0 = fdot2u(q.x, vh0[j], acc0);
                    acc1 = fdot2u(q.y, vh1[j], acc1);
                }
                lg0[r] += acc0;
                lg1[r] += acc1;
            }
            // ---- block max per b ----
            float m0 = fmaxf(lg0[0], lg0[1]);
            float m1 = fmaxf(lg1[0], lg1[1]);
            #pragma unroll
            for (int off = 1; off <= 32; off <<= 1) {
                m0 = fmaxf(m0, __shfl_xor(m0, off));
                m1 = fmaxf(m1, __shfl_xor(m1, off));
            }
            if (lane == 0) { redS[wav] = m0; redS[NW + wav] = m1; }
            __syncthreads();
            if (t < 2) {
                float m = redS[t * NW];
                for (int w = 1; w < NW; ++w) m = fmaxf(m, redS[t * NW + w]);
                mS[t] = m;
            }
            __syncthreads();
            m0 = mS[0]; m1 = mS[1];
            // ---- unnormalized e -> cS2 ----
            const float e00 = __expf(lg0[0] - m0), e01 = __expf(lg0[1] - m0);
            const float e10 = __expf(lg1[0] - m1), e11 = __expf(lg1[1] - m1);
            cS2[t]      = pkh2(e00, e10);
            cS2[t + NT] = pkh2(e01, e11);
            __syncthreads();
        }

        // ---- s-scan: numerator + denominator, n paired (n, n+72) for dot2 ----
        float2 sp0 = {0.f, 0.f}, sp1 = {0.f, 0.f};
        float dp0 = 0.f, dp1 = 0.f;
        #pragma unroll
        for (int cc2 = 0; cc2 < 8; ++cc2) {
            const int n0 = cc2 * 144 + wav * 8 + g_s;
            const int n1 = n0 + 72;
            const uint2 q0 = uhS[j_s * SJ + n0];
            const uint2 q1 = uhS[j_s * SJ + n1];
            unsigned cp0, cp1;
            if (it == 0) { cp0 = ONE2; cp1 = ONE2; }
            else {
                const unsigned e0 = cS2[n0], e1 = cS2[n1];
                cp0 = __builtin_amdgcn_perm(e0, e1, PERM_LO);   // (c_b0[n0], c_b0[n1])
                cp1 = __builtin_amdgcn_perm(e0, e1, PERM_HI);   // (c_b1[n0], c_b1[n1])
                dp0 = fdot2u(cp0, ONE2, dp0);
                dp1 = fdot2u(cp1, ONE2, dp1);
            }
            const unsigned px0 = __builtin_amdgcn_perm(q0.x, q1.x, PERM_LO); // b0, o=2j
            const unsigned py0 = __builtin_amdgcn_perm(q0.x, q1.x, PERM_HI); // b0, o=2j+1
            const unsigned px1 = __builtin_amdgcn_perm(q0.y, q1.y, PERM_LO); // b1
            const unsigned py1 = __builtin_amdgcn_perm(q0.y, q1.y, PERM_HI);
            sp0.x = fdot2u(px0, cp0, sp0.x);
            sp0.y = fdot2u(py0, cp0, sp0.y);
            sp1.x = fdot2u(px1, cp1, sp1.x);
            sp1.y = fdot2u(py1, cp1, sp1.y);
        }
        if (it == 0) { dp0 = 16.f; dp1 = 16.f; }   // c==1: 16 n's per lane

        #pragma unroll
        for (int off = 8; off <= 32; off <<= 1) {
            sp0.x += __shfl_xor(sp0.x, off);
            sp0.y += __shfl_xor(sp0.y, off);
            sp1.x += __shfl_xor(sp1.x, off);
            sp1.y += __shfl_xor(sp1.y, off);
            dp0   += __shfl_xor(dp0,   off);
            dp1   += __shfl_xor(dp1,   off);
        }
        if (lane < 8) {
            redS[(0*NW + wav)*17 + 2*j_s    ] = sp0.x;
            redS[(0*NW + wav)*17 + 2*j_s + 1] = sp0.y;
            redS[(1*NW + wav)*17 + 2*j_s    ] = sp1.x;
            redS[(1*NW + wav)*17 + 2*j_s + 1] = sp1.y;
        }
        if (lane == 0) {
            redS[(0*NW + wav)*17 + 16] = dp0;
            redS[(1*NW + wav)*17 + 16] = dp1;
        }
        __syncthreads();

        // ---- finalize s/d + squash on wave 0 ----
        if (t < 32) {
            const int b = t >> 4, o = t & 15;
            float s = 0.f, d = 0.f;
            #pragma unroll
            for (int w = 0; w < NW; ++w) {
                s += redS[(b*NW + w)*17 + o];
                d += redS[(b*NW + w)*17 + 16];
            }
            s /= d;
            float s2 = s * s;
            #pragma unroll
            for (int off = 1; off <= 8; off <<= 1) s2 += __shfl_xor(s2, off);
            const float scale = (s2 / (1.f + s2)) * rsqrtf(fmaxf(s2, 1e-30f));
            const float v = s * scale;
            vS[b*16 + o] = v;
            if (it == 2) out[((size_t)k * Bsz + b0 + b) * 16 + o] = v;
        }
        if (it == 2) break;
        __syncthreads();

        // ---- broadcast v, packed to half2 for the a-scan dot2 ----
        {
            const float4* vp = (const float4*)vS;
            #pragma unroll
            for (int q4 = 0; q4 < 4; ++q4) {
                const float4 a = vp[q4], b = vp[4 + q4];
                vh0[2*q4]   = pkh2(a.x, a.y);
                vh0[2*q4+1] = pkh2(a.z, a.w);
                vh1[2*q4]   = pkh2(b.x, b.y);
                vh1[2*q4+1] = pkh2(b.z, b.w);
            }
        }
    }
}

extern "C" void kernel_launch(void* const* d_in, const int* in_sizes, int n_in,
                              void* d_out, int out_size, void* d_ws, size_t ws_size,
                              hipStream_t stream) {
    const float* u = (const float*)d_in[0];
    const float* W = (const float*)d_in[1];
    float* out = (float*)d_out;
    const size_t need = (size_t)(W_ELEMS + U_ELEMS) * sizeof(__half);
    if (ws_size >= need) {
        __half* Wh = (__half*)d_ws;
        __half* uh = (__half*)((char*)d_ws + (size_t)W_ELEMS * sizeof(__half));
        cvt_kernel<<<dim3(WBLKS + UBLKS), dim3(256), 0, stream>>>(
            W, u, (unsigned*)Wh, (__half2*)uh);
        digitcaps_kernel<true><<<dim3(128, 10), dim3(NT), 0, stream>>>(
            nullptr, nullptr, uh, Wh, out);
    } else {
        digitcaps_kernel<false><<<dim3(128, 10), dim3(NT), 0, stream>>>(
            u, W, nullptr, nullptr, out);
    }
}

// Round 2
// 128.539 us; speedup vs baseline: 1.1358x; 1.1358x over previous
//
#include <hip/hip_runtime.h>
#include <hip/hip_fp16.h>

#define Bsz 256
#define Nn  1152
#define Kk  10
#define NT  384      // 6 waves; 4 blocks/CU -> 24 waves/CU
#define NW  6
#define S4  1160     // uint stride per o-pair row: 1160 mod 32 = 8 -> s-scan is 2 lanes/bank (free)

#define W_ELEMS (Kk*Nn*128)     // 1474560
#define U_ELEMS (Bsz*Nn*8)      // 2359296

static __device__ __forceinline__ unsigned pkh2(float x, float y) {
    __half2 h = __floats2half2_rn(x, y);
    return *reinterpret_cast<unsigned*>(&h);
}
static __device__ __forceinline__ float2 uph2(unsigned v) {
    __half2 h;
    *reinterpret_cast<unsigned*>(&h) = v;
    return __half22float2(h);
}
static __device__ __forceinline__ void up8(const uint4 q, float f[8]) {
    float2 a = uph2(q.x), b = uph2(q.y), c = uph2(q.z), d = uph2(q.w);
    f[0]=a.x; f[1]=a.y; f[2]=b.x; f[3]=b.y; f[4]=c.x; f[5]=c.y; f[6]=d.x; f[7]=d.y;
}

// fp32 -> fp16 conversion of W then u into workspace (8 elems/thread), layouts unchanged
__global__ void cvt_kernel(const float* __restrict__ W, const float* __restrict__ u,
                           __half2* __restrict__ Wh, __half2* __restrict__ uh) {
    const int idx = blockIdx.x * blockDim.x + threadIdx.x;
    const int wg = W_ELEMS / 8;            // 184320
    const float4* p;
    __half2* o;
    if (idx < wg) {
        p = (const float4*)W + (size_t)idx * 2;
        o = Wh + (size_t)idx * 4;
    } else {
        const int j = idx - wg;            // < 294912
        p = (const float4*)u + (size_t)j * 2;
        o = uh + (size_t)j * 4;
    }
    const float4 a = p[0], b = p[1];
    o[0] = __floats2half2_rn(a.x, a.y);
    o[1] = __floats2half2_rn(a.z, a.w);
    o[2] = __floats2half2_rn(b.x, b.y);
    o[3] = __floats2half2_rn(b.z, b.w);
}

// One block per (b, k). u_hat fp16 in LDS as 8 o-pair rows of unsigned[S4].
// Routing with e-trick softmax (unnormalized exp, denominator carried in redS col 16).
// 4 blocks/CU (LDS ~39.9 KB), 24 waves/CU — occupancy/latency-hiding structure.
template<bool HALF>
__global__ __launch_bounds__(NT, 6)
void digitcaps_kernel(const float* __restrict__ u32, const float* __restrict__ W32,
                      const __half* __restrict__ uh, const __half* __restrict__ Wh,
                      float* __restrict__ out)
{
    const int t    = threadIdx.x;
    const int lane = t & 63;
    const int wav  = t >> 6;
    const int b    = blockIdx.x;     // 0..255
    const int k    = blockIdx.y;     // 0..9

    __shared__ unsigned       uhS[8 * S4];    // 37120 B  half2(o=2j, o=2j+1) per n
    __shared__ unsigned short cS[Nn];         // 2304 B   e per n (half bits)
    __shared__ float          redS[NW * 17];  // 408 B    [wav][16 s-cols + d]
    __shared__ __align__(16) float vS[16];    // 64 B
    __shared__ float          mS[1];          // 4 B
    // total ~39.9 KB -> 4 blocks/CU; VGPR must stay <=~84 for 6 waves/SIMD

    // ---------------- Phase 1: u_hat = u . W ----------------
    {
        const int oh   = t & 1;
        const int nsub = t >> 1;               // 0..191
        for (int r = 0; r < 6; ++r) {
            const int n = r * 192 + nsub;
            float ua[8];
            if (HALF) {
                const uint4 qa = *(const uint4*)(uh + ((size_t)b * Nn + n) * 8);
                up8(qa, ua);
            } else {
                const float4* up0 = (const float4*)(u32 + ((size_t)b * Nn + n) * 8);
                const float4 x0 = up0[0], x1 = up0[1];
                ua[0]=x0.x; ua[1]=x0.y; ua[2]=x0.z; ua[3]=x0.w;
                ua[4]=x1.x; ua[5]=x1.y; ua[6]=x1.z; ua[7]=x1.w;
            }
            float a0[8];
            #pragma unroll
            for (int o = 0; o < 8; ++o) a0[o] = 0.f;
            #pragma unroll
            for (int i = 0; i < 8; ++i) {
                float wv[8];
                if (HALF) {
                    const uint4 qw = *(const uint4*)(Wh + ((size_t)(k * Nn + n)) * 128 + i * 16 + oh * 8);
                    up8(qw, wv);
                } else {
                    const float4* wp = (const float4*)(W32 + ((size_t)k * Nn + n) * 128) + oh * 2 + i * 4;
                    const float4 w0 = wp[0], w1 = wp[1];
                    wv[0]=w0.x; wv[1]=w0.y; wv[2]=w0.z; wv[3]=w0.w;
                    wv[4]=w1.x; wv[5]=w1.y; wv[6]=w1.z; wv[7]=w1.w;
                }
                const float x = ua[i];
                #pragma unroll
                for (int o = 0; o < 8; ++o) a0[o] += x * wv[o];
            }
            #pragma unroll
            for (int jj = 0; jj < 4; ++jj)
                uhS[(oh * 4 + jj) * S4 + n] = pkh2(a0[2*jj], a0[2*jj+1]);
        }
    }
    __syncthreads();

    // ---------------- Phase 2: routing ----------------
    float lg[3] = {0.f, 0.f, 0.f};
    float vv[16];
    const int j_s = lane & 7;
    const int g_s = lane >> 3;

    for (int it = 0; it < 3; ++it) {
        if (it > 0) {
            // ---- a-scan: logits += u_hat . v (rows n = t, t+NT, t+2NT) ----
            #pragma unroll
            for (int r = 0; r < 3; ++r) {
                const int n = t + r * NT;
                float acc = 0.f;
                #pragma unroll
                for (int j = 0; j < 8; ++j) {
                    const float2 f = uph2(uhS[j * S4 + n]);
                    acc += f.x * vv[2*j] + f.y * vv[2*j+1];
                }
                lg[r] += acc;
            }
            // ---- block max ----
            float m = fmaxf(fmaxf(lg[0], lg[1]), lg[2]);
            #pragma unroll
            for (int off = 1; off <= 32; off <<= 1)
                m = fmaxf(m, __shfl_xor(m, off));
            if (lane == 0) redS[wav] = m;
            __syncthreads();
            if (t == 0) {
                float mm = redS[0];
                #pragma unroll
                for (int w = 1; w < NW; ++w) mm = fmaxf(mm, redS[w]);
                mS[0] = mm;
            }
            __syncthreads();
            m = mS[0];
            // ---- unnormalized e -> cS ----
            #pragma unroll
            for (int r = 0; r < 3; ++r) {
                const __half eh = __float2half(__expf(lg[r] - m));
                cS[t + r * NT] = *reinterpret_cast<const unsigned short*>(&eh);
            }
            __syncthreads();
        }

        // ---- s-scan: numerator and denominator together ----
        float2 sp = {0.f, 0.f};
        float dp = 0.f;
        #pragma unroll
        for (int cc = 0; cc < 24; ++cc) {
            const int n = cc * 48 + wav * 8 + g_s;
            float c;
            if (it == 0) c = 1.f;
            else {
                const unsigned short eb = cS[n];
                c = __half2float(*reinterpret_cast<const __half*>(&eb));
            }
            const float2 f = uph2(uhS[j_s * S4 + n]);
            sp.x += c * f.x;
            sp.y += c * f.y;
            dp   += c;
        }
        #pragma unroll
        for (int off = 8; off <= 32; off <<= 1) {
            sp.x += __shfl_xor(sp.x, off);
            sp.y += __shfl_xor(sp.y, off);
            dp   += __shfl_xor(dp,   off);
        }
        if (lane < 8) {
            redS[wav * 17 + 2*j_s    ] = sp.x;
            redS[wav * 17 + 2*j_s + 1] = sp.y;
        }
        if (lane == 0) redS[wav * 17 + 16] = dp;
        __syncthreads();

        // ---- finalize s/d + squash on wave 0 ----
        if (t < 16) {
            const int o = t;
            float s = 0.f, d = 0.f;
            #pragma unroll
            for (int w = 0; w < NW; ++w) {
                s += redS[w * 17 + o];
                d += redS[w * 17 + 16];
            }
            s /= d;
            float s2 = s * s;
            #pragma unroll
            for (int off = 1; off <= 8; off <<= 1) s2 += __shfl_xor(s2, off);
            const float scale = (s2 / (1.f + s2)) * rsqrtf(fmaxf(s2, 1e-30f));
            const float v = s * scale;
            vS[o] = v;
            if (it == 2) out[((size_t)k * Bsz + b) * 16 + o] = v;
        }
        if (it == 2) break;
        __syncthreads();

        // ---- broadcast v to registers ----
        {
            const float4* vp = (const float4*)vS;
            #pragma unroll
            for (int q4 = 0; q4 < 4; ++q4)
                *(float4*)&vv[4*q4] = vp[q4];
        }
    }
}

extern "C" void kernel_launch(void* const* d_in, const int* in_sizes, int n_in,
                              void* d_out, int out_size, void* d_ws, size_t ws_size,
                              hipStream_t stream) {
    const float* u = (const float*)d_in[0];
    const float* W = (const float*)d_in[1];
    float* out = (float*)d_out;
    const size_t need = (size_t)(W_ELEMS + U_ELEMS) * sizeof(__half);
    if (ws_size >= need) {
        __half* Wh = (__half*)d_ws;
        __half* uh = (__half*)((char*)d_ws + (size_t)W_ELEMS * sizeof(__half));
        cvt_kernel<<<dim3((W_ELEMS + U_ELEMS) / 8 / 256), dim3(256), 0, stream>>>(
            W, u, (__half2*)Wh, (__half2*)uh);
        digitcaps_kernel<true><<<dim3(256, 10), dim3(NT), 0, stream>>>(
            nullptr, nullptr, uh, Wh, out);
    } else {
        digitcaps_kernel<false><<<dim3(256, 10), dim3(NT), 0, stream>>>(
            u, W, nullptr, nullptr, out);
    }
}

// Round 3
// 127.334 us; speedup vs baseline: 1.1465x; 1.0095x over previous
//
#include <hip/hip_runtime.h>
#include <hip/hip_fp16.h>

#define Bsz 256
#define Nn  1152
#define Kk  10
#define NT  384      // 6 waves; 4 blocks/CU -> 24 waves/CU
#define NW  6
#define S4  1160     // uint stride per o-pair row: 1160 mod 32 = 8 -> 2 lanes/bank (free)

#define W_ELEMS (Kk*Nn*128)     // 1474560
#define U_ELEMS (Bsz*Nn*8)      // 2359296

typedef _Float16 hf2_t __attribute__((ext_vector_type(2)));

static __device__ __forceinline__ unsigned pkh2(float x, float y) {
    __half2 h = __floats2half2_rn(x, y);
    return *reinterpret_cast<unsigned*>(&h);
}
static __device__ __forceinline__ float2 uph2(unsigned v) {
    __half2 h;
    *reinterpret_cast<unsigned*>(&h) = v;
    return __half22float2(h);
}
// v_dot2_f32_f16: c += a.lo*b.lo + a.hi*b.hi  (f32 accumulate, 1 inst)
static __device__ __forceinline__ float fdot2u(unsigned a, unsigned b, float c) {
    union { unsigned u; hf2_t h; } A, B;
    A.u = a; B.u = b;
    return __builtin_amdgcn_fdot2(A.h, B.h, c, false);
}

#define PERM_LO 0x01000504u   // result = half2(lo16(arg0), lo16(arg1))
#define PERM_HI 0x03020706u   // result = half2(hi16(arg0), hi16(arg1))
#define ONE2    0x3C003C00u   // half2(1, 1)

// fp32 -> fp16 conversion of W then u into workspace (8 elems/thread), layouts unchanged
__global__ void cvt_kernel(const float* __restrict__ W, const float* __restrict__ u,
                           __half2* __restrict__ Wh, __half2* __restrict__ uh) {
    const int idx = blockIdx.x * blockDim.x + threadIdx.x;
    const int wg = W_ELEMS / 8;            // 184320
    const float4* p;
    __half2* o;
    if (idx < wg) {
        p = (const float4*)W + (size_t)idx * 2;
        o = Wh + (size_t)idx * 4;
    } else {
        const int j = idx - wg;            // < 294912
        p = (const float4*)u + (size_t)j * 2;
        o = uh + (size_t)j * 4;
    }
    const float4 a = p[0], b = p[1];
    o[0] = __floats2half2_rn(a.x, a.y);
    o[1] = __floats2half2_rn(a.z, a.w);
    o[2] = __floats2half2_rn(b.x, b.y);
    o[3] = __floats2half2_rn(b.z, b.w);
}

// One block per (b, k). u_hat fp16 in LDS as 8 o-pair rows of unsigned[S4].
// Memory pattern identical to round-2; VALU cut via perm+dot2; 8 barriers, no
// serial single-wave sections (block-max read by all; squash redundant per wave).
template<bool HALF>
__global__ __launch_bounds__(NT, 6)
void digitcaps_kernel(const float* __restrict__ u32, const float* __restrict__ W32,
                      const __half* __restrict__ uh, const __half* __restrict__ Wh,
                      float* __restrict__ out)
{
    const int t    = threadIdx.x;
    const int lane = t & 63;
    const int wav  = t >> 6;
    const int b    = blockIdx.x;     // 0..255
    const int k    = blockIdx.y;     // 0..9

    __shared__ unsigned       uhS[8 * S4];    // 37120 B  half2(o=2j, o=2j+1) per n
    __shared__ unsigned short cS[Nn];         // 2304 B   e per n (half bits)
    __shared__ float          redS[NW * 17];  // 408 B    [wav][16 s-cols + d]
    __shared__ float          mxS[NW];        // 24 B     per-wave logits max (disjoint from redS!)
    // total ~39.9 KB -> 4 blocks/CU; VGPR must stay <=84 for 6 waves/SIMD

    // ---------------- Phase 1: u_hat = u . W ----------------
    {
        const int oh   = t & 1;
        const int nsub = t >> 1;               // 0..191
        for (int r = 0; r < 6; ++r) {
            const int n = r * 192 + nsub;
            float a0[8];
            #pragma unroll
            for (int o = 0; o < 8; ++o) a0[o] = 0.f;
            if (HALF) {
                const uint4 uq = *(const uint4*)(uh + ((size_t)b * Nn + n) * 8);
                const unsigned uw[4] = {uq.x, uq.y, uq.z, uq.w};
                const __half* wbase = Wh + ((size_t)(k * Nn + n)) * 128 + oh * 8;
                #pragma unroll
                for (int p = 0; p < 4; ++p) {
                    // i = 2p and 2p+1, this thread's 8 o's (16B each, coalesced as before)
                    const uint4 qa = *(const uint4*)(wbase + (2 * p    ) * 16);
                    const uint4 qb = *(const uint4*)(wbase + (2 * p + 1) * 16);
                    const unsigned aw[4] = {qa.x, qa.y, qa.z, qa.w};
                    const unsigned bw[4] = {qb.x, qb.y, qb.z, qb.w};
                    #pragma unroll
                    for (int jj = 0; jj < 4; ++jj) {
                        const unsigned wl = __builtin_amdgcn_perm(aw[jj], bw[jj], PERM_LO);
                        const unsigned wh = __builtin_amdgcn_perm(aw[jj], bw[jj], PERM_HI);
                        a0[2*jj]   = fdot2u(wl, uw[p], a0[2*jj]);
                        a0[2*jj+1] = fdot2u(wh, uw[p], a0[2*jj+1]);
                    }
                }
            } else {
                float ua[8];
                const float4* up0 = (const float4*)(u32 + ((size_t)b * Nn + n) * 8);
                const float4 x0 = up0[0], x1 = up0[1];
                ua[0]=x0.x; ua[1]=x0.y; ua[2]=x0.z; ua[3]=x0.w;
                ua[4]=x1.x; ua[5]=x1.y; ua[6]=x1.z; ua[7]=x1.w;
                #pragma unroll
                for (int i = 0; i < 8; ++i) {
                    const float4* wp = (const float4*)(W32 + ((size_t)k * Nn + n) * 128) + oh * 2 + i * 4;
                    const float4 w0 = wp[0], w1 = wp[1];
                    float wv[8];
                    wv[0]=w0.x; wv[1]=w0.y; wv[2]=w0.z; wv[3]=w0.w;
                    wv[4]=w1.x; wv[5]=w1.y; wv[6]=w1.z; wv[7]=w1.w;
                    const float x = ua[i];
                    #pragma unroll
                    for (int o = 0; o < 8; ++o) a0[o] += x * wv[o];
                }
            }
            #pragma unroll
            for (int jj = 0; jj < 4; ++jj)
                uhS[(oh * 4 + jj) * S4 + n] = pkh2(a0[2*jj], a0[2*jj+1]);
        }
    }
    __syncthreads();                                   // B: u_hat ready

    // ---------------- Phase 2: routing ----------------
    float lg[3] = {0.f, 0.f, 0.f};
    unsigned vh[8];                  // v packed half2 per o-pair
    const int j_s = lane & 7;
    const int g_s = lane >> 3;

    for (int it = 0; it < 3; ++it) {
        if (it > 0) {
            // ---- a-scan: logits += u_hat . v (rows n = t, t+NT, t+2NT) ----
            #pragma unroll
            for (int r = 0; r < 3; ++r) {
                const int n = t + r * NT;
                float acc = 0.f;
                #pragma unroll
                for (int j = 0; j < 8; ++j)
                    acc = fdot2u(uhS[j * S4 + n], vh[j], acc);
                lg[r] += acc;
            }
            // ---- per-wave max -> mxS; all threads reduce across waves ----
            float m = fmaxf(fmaxf(lg[0], lg[1]), lg[2]);
            #pragma unroll
            for (int off = 1; off <= 32; off <<= 1)
                m = fmaxf(m, __shfl_xor(m, off));
            if (lane == 0) mxS[wav] = m;
            __syncthreads();                           // B1
            float mm = mxS[0];
            #pragma unroll
            for (int w = 1; w < NW; ++w) mm = fmaxf(mm, mxS[w]);
            // ---- unnormalized e -> cS ----
            #pragma unroll
            for (int r = 0; r < 3; ++r) {
                const __half eh = __float2half(__expf(lg[r] - mm));
                cS[t + r * NT] = *reinterpret_cast<const unsigned short*>(&eh);
            }
            __syncthreads();                           // B2
        }

        // ---- s-scan: numerator + denominator, n paired (n0, n0+48) for dot2 ----
        float2 sp = {0.f, 0.f};
        float dp = 0.f;
        #pragma unroll
        for (int c2 = 0; c2 < 12; ++c2) {
            const int n0 = c2 * 96 + wav * 8 + g_s;
            const int n1 = n0 + 48;
            unsigned cp;
            if (it == 0) cp = ONE2;
            else cp = (unsigned)cS[n0] | ((unsigned)cS[n1] << 16);
            const unsigned q0 = uhS[j_s * S4 + n0];
            const unsigned q1 = uhS[j_s * S4 + n1];
            const unsigned px = __builtin_amdgcn_perm(q0, q1, PERM_LO); // (uh[n0][oe], uh[n1][oe])
            const unsigned py = __builtin_amdgcn_perm(q0, q1, PERM_HI); // (uh[n0][oo], uh[n1][oo])
            sp.x = fdot2u(px, cp, sp.x);
            sp.y = fdot2u(py, cp, sp.y);
            dp   = fdot2u(cp, ONE2, dp);
        }
        #pragma unroll
        for (int off = 8; off <= 32; off <<= 1) {
            sp.x += __shfl_xor(sp.x, off);
            sp.y += __shfl_xor(sp.y, off);
            dp   += __shfl_xor(dp,   off);
        }
        if (lane < 8) {
            redS[wav * 17 + 2*j_s    ] = sp.x;
            redS[wav * 17 + 2*j_s + 1] = sp.y;
        }
        if (lane == 0) redS[wav * 17 + 16] = dp;
        __syncthreads();                               // B3

        // ---- finalize s/d + squash, redundantly on EVERY wave (no barrier after) ----
        {
            const int o = lane & 15;
            float s = 0.f, d = 0.f;
            #pragma unroll
            for (int w = 0; w < NW; ++w) {
                s += redS[w * 17 + o];                 // broadcast reads
                d += redS[w * 17 + 16];
            }
            s /= d;
            float s2 = s * s;
            #pragma unroll
            for (int off = 1; off <= 8; off <<= 1) s2 += __shfl_xor(s2, off);
            const float scale = (s2 / (1.f + s2)) * rsqrtf(fmaxf(s2, 1e-30f));
            const float v = s * scale;
            if (it == 2) {
                if (wav == 0 && lane < 16)
                    out[((size_t)k * Bsz + b) * 16 + lane] = v;
            } else {
                // broadcast v[0..15] into packed half2 registers via shfl (no LDS, no barrier)
                #pragma unroll
                for (int j = 0; j < 8; ++j)
                    vh[j] = pkh2(__shfl(v, 2*j), __shfl(v, 2*j + 1));
            }
        }
        // next a-scan reads only uhS (static) + vh (regs); lane0's mxS write is the
        // only LDS write before B1 and mxS is disjoint from redS -> no extra barrier
    }
}

extern "C" void kernel_launch(void* const* d_in, const int* in_sizes, int n_in,
                              void* d_out, int out_size, void* d_ws, size_t ws_size,
                              hipStream_t stream) {
    const float* u = (const float*)d_in[0];
    const float* W = (const float*)d_in[1];
    float* out = (float*)d_out;
    const size_t need = (size_t)(W_ELEMS + U_ELEMS) * sizeof(__half);
    if (ws_size >= need) {
        __half* Wh = (__half*)d_ws;
        __half* uh = (__half*)((char*)d_ws + (size_t)W_ELEMS * sizeof(__half));
        cvt_kernel<<<dim3((W_ELEMS + U_ELEMS) / 8 / 256), dim3(256), 0, stream>>>(
            W, u, (__half2*)Wh, (__half2*)uh);
        digitcaps_kernel<true><<<dim3(256, 10), dim3(NT), 0, stream>>>(
            nullptr, nullptr, uh, Wh, out);
    } else {
        digitcaps_kernel<false><<<dim3(256, 10), dim3(NT), 0, stream>>>(
            u, W, nullptr, nullptr, out);
    }
}